// Round 6
// baseline (46622.757 us; speedup 1.0000x reference)
//
#include <hip/hip_runtime.h>
#include <hip/hip_fp16.h>

#define B_ 128
#define T_ 512
#define E_ 128
#define D_ 128

// exp2(C2*x) == e^(2x);  L2E = log2(e)
#define C2f 2.885390081777927f
#define L2E 1.4426950408889634f

typedef float f32x2 __attribute__((ext_vector_type(2)));

__device__ __forceinline__ float rcpf_(float x){ return __builtin_amdgcn_rcpf(x); }
__device__ __forceinline__ float ex2_(float x){ return __builtin_amdgcn_exp2f(x); }

// decode 8 fp8(e4m3) packed in uint2 -> 8 floats
__device__ __forceinline__ void cvt8(uint2 v, float* f){
    f32x2 a = __builtin_amdgcn_cvt_pk_f32_fp8(v.x, false);
    f32x2 b = __builtin_amdgcn_cvt_pk_f32_fp8(v.x, true);
    f32x2 c = __builtin_amdgcn_cvt_pk_f32_fp8(v.y, false);
    f32x2 d = __builtin_amdgcn_cvt_pk_f32_fp8(v.y, true);
    f[0]=a.x; f[1]=a.y; f[2]=b.x; f[3]=b.y; f[4]=c.x; f[5]=c.y; f[6]=d.x; f[7]=d.y;
}

__global__ __launch_bounds__(256) void transpose_half(const float* __restrict__ in,
                                                      __half* __restrict__ out,
                                                      int K, int N){
    __shared__ float tile[32][33];
    int n0 = blockIdx.x * 32, k0 = blockIdx.y * 32;
    int tx = threadIdx.x & 31, ty = threadIdx.x >> 5;
    #pragma unroll
    for (int i = ty; i < 32; i += 8)
        tile[i][tx] = in[(size_t)(k0 + i) * N + n0 + tx];
    __syncthreads();
    #pragma unroll
    for (int i = ty; i < 32; i += 8)
        out[(size_t)(n0 + i) * K + k0 + tx] = __float2half(tile[tx][i]);
}

__global__ __launch_bounds__(256) void enc_to_half(const float* __restrict__ in,
                                                   __half* __restrict__ out){
    int i = (blockIdx.x * 256 + threadIdx.x) * 4;
    float4 v = *(const float4*)(in + i);
    *(__half2*)(out + i)     = __floats2half2_rn(v.x, v.y);
    *(__half2*)(out + i + 2) = __floats2half2_rn(v.z, v.w);
}

// P[b][n][t] = clamp(exp2(C2*(enc[b][t][:]·Ua[:][n] + bu[n])), <=440) as fp8 e4m3
__global__ __launch_bounds__(256) void uenc_kernel(const float* __restrict__ enc,
                                                   const float* __restrict__ Ua,
                                                   const float* __restrict__ bu,
                                                   unsigned char* __restrict__ P){
    int b = blockIdx.z;
    int t0 = blockIdx.x * 64;
    int n0 = blockIdx.y * 64;
    int tt = threadIdx.x & 63;
    int ng = threadIdx.x >> 6;
    const float* erow = enc + ((size_t)b * T_ + (t0 + tt)) * E_;
    const float* uap  = Ua + n0 + ng * 16;
    float acc[16];
    #pragma unroll
    for (int i = 0; i < 16; i++) acc[i] = 0.f;
    #pragma unroll 2
    for (int e0 = 0; e0 < E_; e0 += 4){
        float4 av = *(const float4*)(erow + e0);
        #pragma unroll
        for (int ee = 0; ee < 4; ee++){
            float a = (ee==0)?av.x:(ee==1)?av.y:(ee==2)?av.z:av.w;
            const float4* u4 = (const float4*)(uap + (size_t)(e0+ee) * T_);
            float4 x0 = u4[0], x1 = u4[1], x2 = u4[2], x3 = u4[3];
            acc[0]  = fmaf(a, x0.x, acc[0]);  acc[1]  = fmaf(a, x0.y, acc[1]);
            acc[2]  = fmaf(a, x0.z, acc[2]);  acc[3]  = fmaf(a, x0.w, acc[3]);
            acc[4]  = fmaf(a, x1.x, acc[4]);  acc[5]  = fmaf(a, x1.y, acc[5]);
            acc[6]  = fmaf(a, x1.z, acc[6]);  acc[7]  = fmaf(a, x1.w, acc[7]);
            acc[8]  = fmaf(a, x2.x, acc[8]);  acc[9]  = fmaf(a, x2.y, acc[9]);
            acc[10] = fmaf(a, x2.z, acc[10]); acc[11] = fmaf(a, x2.w, acc[11]);
            acc[12] = fmaf(a, x3.x, acc[12]); acc[13] = fmaf(a, x3.y, acc[13]);
            acc[14] = fmaf(a, x3.z, acc[14]); acc[15] = fmaf(a, x3.w, acc[15]);
        }
    }
    int nb = n0 + ng * 16;
    #pragma unroll
    for (int i = 0; i < 16; i++){
        float u = acc[i] + bu[nb + i];
        float v = fminf(ex2_(C2f * u), 440.f);
        int pk = __builtin_amdgcn_cvt_pk_fp8_f32(v, v, 0, false);
        P[(size_t)b * T_ * T_ + (size_t)(nb + i) * T_ + t0 + tt] = (unsigned char)(pk & 0xff);
    }
}

__device__ __forceinline__ void dot8(float& acc, uint4 wv, float4 ha, float4 hb){
    float2 f0 = __half22float2(*reinterpret_cast<__half2*>(&wv.x));
    float2 f1 = __half22float2(*reinterpret_cast<__half2*>(&wv.y));
    float2 f2 = __half22float2(*reinterpret_cast<__half2*>(&wv.z));
    float2 f3 = __half22float2(*reinterpret_cast<__half2*>(&wv.w));
    acc = fmaf(ha.x, f0.x, acc); acc = fmaf(ha.y, f0.y, acc);
    acc = fmaf(ha.z, f1.x, acc); acc = fmaf(ha.w, f1.y, acc);
    acc = fmaf(hb.x, f2.x, acc); acc = fmaf(hb.y, f2.y, acc);
    acc = fmaf(hb.z, f3.x, acc); acc = fmaf(hb.w, f3.y, acc);
}

// 128 blocks x 1024 threads, one per batch element. No inter-block sync.
// LDS ~156 KB -> 1 block/CU. waves_per_eu(4,4) pins occupancy target so the
// compiler can use the full 128-VGPR budget (r5's spill fix).
__global__ __attribute__((amdgpu_waves_per_eu(4, 4))) __launch_bounds__(1024)
void decoder_kernel(
    const float* __restrict__ enc, const __half* __restrict__ enc_h, int use_f16,
    const float* __restrict__ labels,
    const float* __restrict__ init_h, const float* __restrict__ init_c,
    const float* __restrict__ Va,
    const float* __restrict__ ba, const float* __restrict__ bl,
    const float* __restrict__ Wc, const float* __restrict__ bc,
    const float* __restrict__ Wk,
    const float* __restrict__ W1, const float* __restrict__ b1,
    const float* __restrict__ W2, const float* __restrict__ b2,
    const __half* __restrict__ Wa_t, const __half* __restrict__ Wr_t,
    const unsigned char* __restrict__ Pw,
    float* __restrict__ out)
{
    __shared__ __align__(16) uint2 Plds2[224 * 64];   // 112 KB: fp8 P rows (14 per 32-row group)
    __shared__ __align__(16) float scratch[8192];     // 32 KB partials
    __shared__ __align__(16) float Q_s[512];
    __shared__ __align__(16) float Va2_s[512];
    __shared__ __align__(16) float sc[512];           // softmax numerators p[t]
    __shared__ __align__(16) float rz_s[512];
    __shared__ __align__(16) float hc_s[256];         // h [0,128), c [128,256)
    __shared__ __align__(16) float ctx_s[128];
    __shared__ __align__(16) float ba_s[512];
    __shared__ float Wc_s[132];
    __shared__ float red[20];

    const int tid = threadIdx.x;
    const int b = blockIdx.x;

    // ---- Wa held in registers: row n = tid&511, k-half kh = tid>>9 (128 halves)
    uint4 wa_reg[16];
    {
        int n = tid & 511, kh = tid >> 9;
        const uint4* wa = (const uint4*)(Wa_t + (size_t)n * 256 + kh * 128);
        #pragma unroll
        for (int i = 0; i < 16; i++) wa_reg[i] = wa[i];
    }

    if (tid < 128){
        hc_s[tid]       = init_h[b*128 + tid];
        hc_s[128 + tid] = init_c[b*128 + tid];
    }
    if (tid < 512){
        Va2_s[tid] = -2.f * Va[tid];
        ba_s[tid]  = ba[tid];
    }
    if (tid < 129) Wc_s[tid] = Wc[tid];
    if (tid == 129) Wc_s[130] = bc[0];

    const unsigned char* Pb = Pw + (size_t)b * T_ * T_;

    // LDS P rows: lds row r = 14g + j  <->  n = 32g + j (j<14);  512 B/row = 64 uint2
    {
        int wid = tid >> 6, lane = tid & 63;
        for (int r = wid; r < 224; r += 16){
            int g = r / 14, j = r - 14 * g;
            Plds2[(size_t)r * 64 + lane] =
                *((const uint2*)(Pb + (size_t)(32*g + j) * 512) + lane);
        }
    }
    __syncthreads();

    const float4* hc4 = (const float4*)hc_s;

    for (int t = 0; t < T_; t++){
        // ---- phase A: s-partials (Wa from registers) + rz-partials (Wr streamed)
        {
            int n = tid & 511, kh = tid >> 9;
            float acc = 0.f;
            #pragma unroll
            for (int i = 0; i < 16; i++)
                dot8(acc, wa_reg[i], hc4[kh*32 + 2*i], hc4[kh*32 + 2*i + 1]);
            scratch[kh*512 + n] = acc;
            float accr = 0.f;
            const uint4* wr = (const uint4*)(Wr_t + (size_t)n * 128 + kh * 64);
            #pragma unroll
            for (int i = 0; i < 8; i++)
                dot8(accr, wr[i], hc4[kh*16 + 2*i], hc4[kh*16 + 2*i + 1]);
            scratch[1024 + kh*512 + n] = accr;
        }
        __syncthreads();                                         // b1
        if (tid < 512){
            float s = scratch[tid] + scratch[512 + tid] + ba_s[tid];
            Q_s[tid] = ex2_(C2f * s);
        } else {
            int m = tid - 512;
            rz_s[m] = scratch[1024 + m] + scratch[1536 + m];
            if (tid == 1020) red[18] = labels[(size_t)b * T_ + t];
        }
        __syncthreads();                                         // b2

        // ---- phase B: score[t'] partials over 32-row n-groups; rcp-tree (1 rcp / 4 rows)
        {
            int q = tid & 63, g = tid >> 6;
            const uint2* Pl  = Plds2 + (size_t)(14*g) * 64 + q;
            const uint2* Pg2 = (const uint2*)(Pb + (size_t)(32*g) * 512) + q;
            const float* Qp = Q_s + 32*g;
            const float* Ap = Va2_s + 32*g;
            float acc[8];
            #pragma unroll
            for (int k = 0; k < 8; k++) acc[k] = 0.f;

            #define QUAD(v0,v1,v2,v3,J) { \
                float f0[8], f1[8], f2[8], f3[8]; \
                cvt8(v0, f0); cvt8(v1, f1); cvt8(v2, f2); cvt8(v3, f3); \
                float q0=Qp[J+0], q1=Qp[J+1], q2=Qp[J+2], q3=Qp[J+3]; \
                float a0=Ap[J+0], a1=Ap[J+1], a2=Ap[J+2], a3=Ap[J+3]; \
                _Pragma("unroll") \
                for (int k = 0; k < 8; k++){ \
                    float d0=fmaf(f0[k],q0,1.f), d1=fmaf(f1[k],q1,1.f); \
                    float d2=fmaf(f2[k],q2,1.f), d3=fmaf(f3[k],q3,1.f); \
                    float n01=fmaf(a0,d1,a1*d0), d01=d0*d1; \
                    float n23=fmaf(a2,d3,a3*d2), d23=d2*d3; \
                    acc[k]=fmaf(fmaf(n01,d23,n23*d01), rcpf_(d01*d23), acc[k]); \
                } }

            QUAD(Pl[0*64],  Pl[1*64],  Pl[2*64],  Pl[3*64],  0);
            QUAD(Pl[4*64],  Pl[5*64],  Pl[6*64],  Pl[7*64],  4);
            QUAD(Pl[8*64],  Pl[9*64],  Pl[10*64], Pl[11*64], 8);
            QUAD(Pl[12*64], Pl[13*64], Pg2[(size_t)14*64], Pg2[(size_t)15*64], 12);
            QUAD(Pg2[(size_t)16*64], Pg2[(size_t)17*64], Pg2[(size_t)18*64], Pg2[(size_t)19*64], 16);
            QUAD(Pg2[(size_t)20*64], Pg2[(size_t)21*64], Pg2[(size_t)22*64], Pg2[(size_t)23*64], 20);
            QUAD(Pg2[(size_t)24*64], Pg2[(size_t)25*64], Pg2[(size_t)26*64], Pg2[(size_t)27*64], 24);
            QUAD(Pg2[(size_t)28*64], Pg2[(size_t)29*64], Pg2[(size_t)30*64], Pg2[(size_t)31*64], 28);
            #undef QUAD

            float4* o = (float4*)(scratch + g*512 + q*8);
            o[0] = make_float4(acc[0], acc[1], acc[2], acc[3]);
            o[1] = make_float4(acc[4], acc[5], acc[6], acc[7]);
        }
        __syncthreads();                                         // b3
        // ---- B-reduce: score -> p = exp(score); wave psums -> red[0..7]
        if (tid < 512){
            float v = 0.f;
            #pragma unroll
            for (int g = 0; g < 16; g++) v += scratch[g*512 + tid];
            float p = ex2_(v * L2E);
            sc[tid] = p;
            float ss = p;
            #pragma unroll
            for (int off = 32; off; off >>= 1) ss += __shfl_xor(ss, off);
            if ((tid & 63) == 0) red[tid >> 6] = ss;
        }
        __syncthreads();                                         // b4

        // ---- phase C: ctx partials (raw p; normalization folded in later)
        {
            int eq = tid & 31, tg = tid >> 5;
            int row0 = tg * 16;
            float4 acc4 = make_float4(0.f, 0.f, 0.f, 0.f);
            if (use_f16){
                const uint2* ep = (const uint2*)(enc_h + ((size_t)b*T_ + row0)*E_) + eq;
                #pragma unroll
                for (int i = 0; i < 16; i++){
                    float w = sc[row0 + i];
                    uint2 ev = ep[(size_t)i * 32];
                    float2 e01 = __half22float2(*reinterpret_cast<__half2*>(&ev.x));
                    float2 e23 = __half22float2(*reinterpret_cast<__half2*>(&ev.y));
                    acc4.x = fmaf(w, e01.x, acc4.x); acc4.y = fmaf(w, e01.y, acc4.y);
                    acc4.z = fmaf(w, e23.x, acc4.z); acc4.w = fmaf(w, e23.y, acc4.w);
                }
            } else {
                const float4* ep = (const float4*)(enc + ((size_t)b*T_ + row0)*E_) + eq;
                #pragma unroll
                for (int i = 0; i < 16; i++){
                    float w = sc[row0 + i];
                    float4 ev = ep[(size_t)i * 32];
                    acc4.x = fmaf(w, ev.x, acc4.x); acc4.y = fmaf(w, ev.y, acc4.y);
                    acc4.z = fmaf(w, ev.z, acc4.z); acc4.w = fmaf(w, ev.w, acc4.w);
                }
            }
            *(float4*)(scratch + tg*128 + eq*4) = acc4;
        }
        __syncthreads();                                         // b5
        // ---- C-reduce: ctx = (sum partials)/denom; y-dot partials -> red[16..17]
        if (tid < 128){
            float dn = red[0];
            #pragma unroll
            for (int i = 1; i < 8; i++) dn += red[i];
            float s = 0.f;
            #pragma unroll
            for (int tg = 0; tg < 32; tg++) s += scratch[tg*128 + tid];
            float ctxv = s * rcpf_(dn);
            ctx_s[tid] = ctxv;
            float yp = ctxv * Wc_s[1 + tid];
            #pragma unroll
            for (int off = 32; off; off >>= 1) yp += __shfl_xor(yp, off);
            if ((tid & 63) == 0) red[16 + (tid >> 6)] = yp;
        }
        __syncthreads();                                         // b6
        // ---- gates (Keras i,f,g,o); bl/Wk from global (L1-resident)
        if (tid < 128){
            float y = fmaf(red[18], Wc_s[0], red[16] + red[17] + Wc_s[130]);
            float zi = rz_s[tid]       + bl[tid]       + y * Wk[tid];
            float zf = rz_s[128 + tid] + bl[128 + tid] + y * Wk[128 + tid];
            float zg = rz_s[256 + tid] + bl[256 + tid] + y * Wk[256 + tid];
            float zo = rz_s[384 + tid] + bl[384 + tid] + y * Wk[384 + tid];
            float si = rcpf_(1.f + ex2_(-L2E * zi));
            float sf = rcpf_(1.f + ex2_(-L2E * zf));
            float so = rcpf_(1.f + ex2_(-L2E * zo));
            float tg_ = 1.f - 2.f * rcpf_(ex2_(C2f * zg) + 1.f);
            float cn = sf * hc_s[128 + tid] + si * tg_;
            float tc = 1.f - 2.f * rcpf_(ex2_(C2f * cn) + 1.f);
            hc_s[128 + tid] = cn;
            hc_s[tid] = so * tc;
        }
        __syncthreads();                                         // b7
    }

    // ---- epilogue: pred = ([h, ctx] @ W1 + b1) @ W2 + b2
    if (tid < 128){
        float acc = b1[tid];
        for (int k = 0; k < 128; k++) acc = fmaf(hc_s[k],  W1[k*128 + tid], acc);
        for (int k = 0; k < 128; k++) acc = fmaf(ctx_s[k], W1[(128+k)*128 + tid], acc);
        scratch[tid] = acc * W2[tid];
    }
    __syncthreads();
    if (tid < 64){
        float a = scratch[tid] + scratch[64 + tid];
        #pragma unroll
        for (int off = 32; off; off >>= 1) a += __shfl_xor(a, off);
        if (tid == 0) out[b] = a + b2[0];
    }
}

extern "C" void kernel_launch(void* const* d_in, const int* in_sizes, int n_in,
                              void* d_out, int out_size, void* d_ws, size_t ws_size,
                              hipStream_t stream){
    const float* enc      = (const float*)d_in[0];
    const float* labels   = (const float*)d_in[1];
    const float* init_h   = (const float*)d_in[2];
    const float* init_c   = (const float*)d_in[3];
    const float* Wa = (const float*)d_in[5];
    const float* ba = (const float*)d_in[6];
    const float* Ua = (const float*)d_in[7];
    const float* bu = (const float*)d_in[8];
    const float* Va = (const float*)d_in[9];
    // d_in[10] = bv: softmax-shift-invariant, unused
    const float* Wc = (const float*)d_in[11];
    const float* bc = (const float*)d_in[12];
    const float* Wk = (const float*)d_in[13];
    const float* Wr = (const float*)d_in[14];
    const float* bl = (const float*)d_in[15];
    const float* W1 = (const float*)d_in[16];
    const float* b1 = (const float*)d_in[17];
    const float* W2 = (const float*)d_in[18];
    const float* b2 = (const float*)d_in[19];

    char* ws = (char*)d_ws;
    const size_t szP   = (size_t)B_ * T_ * T_;         // fp8: 33,554,432
    const size_t szWa  = 512 * 256 * 2;                // 262,144
    const size_t szWr  = 512 * 128 * 2;                // 131,072
    const size_t base  = szP + szWa + szWr;            // 33,947,648
    const size_t szEnc = (size_t)B_ * T_ * E_ * 2;     // 16,777,216

    unsigned char* P = (unsigned char*)ws;
    __half* Wa_t = (__half*)(ws + szP);
    __half* Wr_t = (__half*)(ws + szP + szWa);

    int use_f16 = (ws_size >= base + szEnc) ? 1 : 0;
    __half* enc_h = (__half*)(ws + base);

    transpose_half<<<dim3(16, 8, 1), 256, 0, stream>>>(Wa, Wa_t, 256, 512);
    transpose_half<<<dim3(16, 4, 1), 256, 0, stream>>>(Wr, Wr_t, 128, 512);
    if (use_f16)
        enc_to_half<<<8192, 256, 0, stream>>>(enc, enc_h);

    dim3 g1(T_/64, T_/64, B_);
    uenc_kernel<<<g1, 256, 0, stream>>>(enc, Ua, bu, P);

    decoder_kernel<<<B_, 1024, 0, stream>>>(enc, enc_h, use_f16,
        labels, init_h, init_c, Va, ba, bl, Wc, bc, Wk, W1, b1, W2, b2,
        Wa_t, Wr_t, P, (float*)d_out);
}